// Round 1
// baseline (1926.033 us; speedup 1.0000x reference)
//
#include <hip/hip_runtime.h>

#define M_TOTAL 65536   // B*T rows
#define DDIM    128     // latent dim (GEMM K)
#define KCODES  1024    // codebook size (GEMM N)
#define NQ      8       // RVQ stages
#define MROWS   64      // rows per block
#define NCHUNK  128     // codes per n-chunk
#define KC      32      // k-dims per LDS staging chunk
#define AS_STRIDE 132   // padded LDS strides (bank-conflict break, keeps 16B align)
#define ES_STRIDE 132

// ||e||^2 per codeword: one wave per codeword, shuffle reduce.
__global__ __launch_bounds__(256) void enorm_kernel(const float* __restrict__ embed,
                                                    float* __restrict__ enorm) {
  int c = blockIdx.x * 4 + (threadIdx.x >> 6);
  int lane = threadIdx.x & 63;
  const float* e = embed + (size_t)c * DDIM;
  float v0 = e[lane];
  float v1 = e[lane + 64];
  float s = fmaf(v0, v0, v1 * v1);
  #pragma unroll
  for (int off = 32; off > 0; off >>= 1) s += __shfl_down(s, off);
  if (lane == 0) enorm[c] = s;
}

// One RVQ stage: 64 rows/block vs all 1024 codes; argmax(2*dot - ||e||^2),
// first-occurrence tie-break; then residual update (block owns its rows ->
// in-place residual buffer is race-free).
__global__ __launch_bounds__(256) void rvq_stage_kernel(
    const float* __restrict__ rin, float* __restrict__ rout,
    const float* __restrict__ embed,   // [KCODES][DDIM] for this stage
    const float* __restrict__ enorm,   // [KCODES]
    int* __restrict__ codes)           // [M_TOTAL] slice for this stage
{
  __shared__ float smem[MROWS * AS_STRIDE + KC * ES_STRIDE + NCHUNK];
  float* As  = smem;                         // [64][132] row-major, full K
  float* Es  = smem + MROWS * AS_STRIDE;     // [32][132] k-major code chunk
  float* Ens = Es + KC * ES_STRIDE;          // [128] e-norms of current chunk
  // Reduction overlay (reuses Es region after compute is done):
  float* red_v = Es;                         // [64][17]
  int*   red_i = (int*)(Es + 1088);          // [64][17]
  int*   bcode = (int*)(Es + 2176);          // [64]

  const int tid = threadIdx.x;
  const int tx = tid & 15;   // code group
  const int ty = tid >> 4;   // row group
  const int row_base = blockIdx.x * MROWS;

  // Stage A tile (residual rows), float4, row-major.
  #pragma unroll
  for (int it = 0; it < 8; ++it) {
    int idx = it * 256 + tid;
    int r = idx >> 5;          // 32 float4 per row
    int f4 = idx & 31;
    float4 v = *(const float4*)(rin + (size_t)(row_base + r) * DDIM + f4 * 4);
    *(float4*)(As + r * AS_STRIDE + f4 * 4) = v;
  }

  float best[4];
  int bidx[4];
  #pragma unroll
  for (int i = 0; i < 4; ++i) { best[i] = -3.0e38f; bidx[i] = 0x7fffffff; }

  for (int nc = 0; nc < KCODES / NCHUNK; ++nc) {
    float acc[4][8];
    #pragma unroll
    for (int i = 0; i < 4; ++i)
      #pragma unroll
      for (int j = 0; j < 8; ++j) acc[i][j] = 0.0f;

    for (int kc = 0; kc < DDIM / KC; ++kc) {
      __syncthreads();
      // Stage E chunk transposed to k-major: Es[k][code]
      #pragma unroll
      for (int it = 0; it < 4; ++it) {
        int idx = it * 256 + tid;
        int c = idx >> 3;
        int f4 = idx & 7;
        float4 v = *(const float4*)(embed + (size_t)(nc * NCHUNK + c) * DDIM + kc * KC + f4 * 4);
        Es[(f4 * 4 + 0) * ES_STRIDE + c] = v.x;
        Es[(f4 * 4 + 1) * ES_STRIDE + c] = v.y;
        Es[(f4 * 4 + 2) * ES_STRIDE + c] = v.z;
        Es[(f4 * 4 + 3) * ES_STRIDE + c] = v.w;
      }
      if (kc == 0 && tid < NCHUNK) Ens[tid] = enorm[nc * NCHUNK + tid];
      __syncthreads();

      const float* pa0 = As + (ty * 4 + 0) * AS_STRIDE + kc * KC;
      const float* pa1 = As + (ty * 4 + 1) * AS_STRIDE + kc * KC;
      const float* pa2 = As + (ty * 4 + 2) * AS_STRIDE + kc * KC;
      const float* pa3 = As + (ty * 4 + 3) * AS_STRIDE + kc * KC;
      #pragma unroll 8
      for (int k = 0; k < KC; ++k) {
        // codes 4tx..4tx+3 and 64+4tx..64+4tx+3 -> conflict-free b128 reads
        float4 b0 = *(const float4*)(Es + k * ES_STRIDE + 4 * tx);
        float4 b1 = *(const float4*)(Es + k * ES_STRIDE + 64 + 4 * tx);
        float a0 = pa0[k], a1 = pa1[k], a2 = pa2[k], a3 = pa3[k];
        float bb[8] = {b0.x, b0.y, b0.z, b0.w, b1.x, b1.y, b1.z, b1.w};
        #pragma unroll
        for (int j = 0; j < 8; ++j) {
          acc[0][j] = fmaf(a0, bb[j], acc[0][j]);
          acc[1][j] = fmaf(a1, bb[j], acc[1][j]);
          acc[2][j] = fmaf(a2, bb[j], acc[2][j]);
          acc[3][j] = fmaf(a3, bb[j], acc[3][j]);
        }
      }
    }

    // Epilogue for this code chunk: dist = 2*dot - ||e||^2, running argmax.
    #pragma unroll
    for (int j = 0; j < 8; ++j) {
      int c_local = (j < 4) ? (4 * tx + j) : (64 + 4 * tx + j - 4);
      float en = Ens[c_local];
      int cg = nc * NCHUNK + c_local;
      #pragma unroll
      for (int i = 0; i < 4; ++i) {
        float dist = 2.0f * acc[i][j] - en;
        if (dist > best[i] || (dist == best[i] && cg < bidx[i])) {
          best[i] = dist; bidx[i] = cg;
        }
      }
    }
  }

  __syncthreads();   // done with Es/Ens; overlay reduction arrays
  #pragma unroll
  for (int i = 0; i < 4; ++i) {
    red_v[(ty * 4 + i) * 17 + tx] = best[i];
    red_i[(ty * 4 + i) * 17 + tx] = bidx[i];
  }
  __syncthreads();
  if (tid < MROWS) {
    float bv = red_v[tid * 17];
    int bi = red_i[tid * 17];
    #pragma unroll
    for (int t = 1; t < 16; ++t) {
      float v = red_v[tid * 17 + t];
      int ix = red_i[tid * 17 + t];
      if (v > bv || (v == bv && ix < bi)) { bv = v; bi = ix; }
    }
    codes[row_base + tid] = bi;
    bcode[tid] = bi;
  }
  __syncthreads();

  // Residual update: rout = As - embed[code], coalesced.
  #pragma unroll
  for (int it = 0; it < 32; ++it) {
    int idx = it * 256 + tid;
    int r = idx >> 7;
    int d = idx & 127;
    float e = embed[(size_t)bcode[r] * DDIM + d];
    rout[(size_t)(row_base + r) * DDIM + d] = As[r * AS_STRIDE + d] - e;
  }
}

extern "C" void kernel_launch(void* const* d_in, const int* in_sizes, int n_in,
                              void* d_out, int out_size, void* d_ws, size_t ws_size,
                              hipStream_t stream) {
  (void)in_sizes; (void)n_in; (void)out_size;
  const float* x = (const float*)d_in[0];
  const float* embed = (const float*)d_in[1];
  int* codes = (int*)d_out;

  const size_t resid_elems = (size_t)M_TOTAL * DDIM;
  const bool ws_ok = ws_size >= (resid_elems + (size_t)NQ * KCODES) * sizeof(float);
  // Residual buffer in workspace; fallback: mutate d_in[0] in place (harness
  // restores inputs from a pristine copy before every timed launch).
  float* resid = ws_ok ? (float*)d_ws : (float*)d_in[0];
  float* enorm = ws_ok ? ((float*)d_ws + resid_elems) : (float*)d_ws;

  enorm_kernel<<<dim3(NQ * KCODES / 4), dim3(256), 0, stream>>>(embed, enorm);

  for (int q = 0; q < NQ; ++q) {
    const float* rin = (q == 0) ? x : resid;
    rvq_stage_kernel<<<dim3(M_TOTAL / MROWS), dim3(256), 0, stream>>>(
        rin, resid,
        embed + (size_t)q * KCODES * DDIM,
        enorm + (size_t)q * KCODES,
        codes + (size_t)q * M_TOTAL);
  }
}

// Round 2
// 1817.012 us; speedup vs baseline: 1.0600x; 1.0600x over previous
//
#include <hip/hip_runtime.h>

#define M_TOTAL 65536   // B*T rows
#define DDIM    128     // latent dim (GEMM K)
#define KCODES  1024    // codebook size (GEMM N)
#define NQ      8       // RVQ stages
#define MROWS   64      // rows per block
#define NCHUNK  256     // codes per n-chunk (acc registers cover 8 of these per thread)
#define KC      16      // k-dims per Es staging chunk
#define AS_STRIDE 68    // As k-major [128][68]: 68%32=4 -> conflict-free b128 reads, 16B aligned
#define ES_STRIDE 260   // Es k-major [16][260]: 260%32=4 -> conflict-free b128 reads, 16B aligned

// ||e||^2 per codeword: one wave per codeword, shuffle reduce.
__global__ __launch_bounds__(256) void enorm_kernel(const float* __restrict__ embed,
                                                    float* __restrict__ enorm) {
  int c = blockIdx.x * 4 + (threadIdx.x >> 6);
  int lane = threadIdx.x & 63;
  const float* e = embed + (size_t)c * DDIM;
  float v0 = e[lane];
  float v1 = e[lane + 64];
  float s = fmaf(v0, v0, v1 * v1);
  #pragma unroll
  for (int off = 32; off > 0; off >>= 1) s += __shfl_down(s, off);
  if (lane == 0) enorm[c] = s;
}

// One RVQ stage. 64 rows/block vs all 1024 codes.
// Thread tile: 8 rows x 8 codes (tx=tid&31 -> codes {4tx..4tx+3, 128+4tx..+3} of the
// 256-code chunk; ty=tid>>5 -> rows ty*8..ty*8+7). A and E both k-major in LDS so all
// inner-loop reads are ds_read_b128 with 2-way-max bank aliasing (free).
// K-accumulation order identical to the verified round-1 kernel -> bit-identical dots.
__global__ __launch_bounds__(256, 3) void rvq_stage_kernel(
    const float* __restrict__ rin, float* __restrict__ rout,
    const float* __restrict__ embed,   // [KCODES][DDIM] for this stage
    const float* __restrict__ enorm,   // [KCODES]
    int* __restrict__ codes)           // [M_TOTAL] slice for this stage
{
  __shared__ float smem[DDIM * AS_STRIDE + KC * ES_STRIDE + NCHUNK]; // 52480 B -> 3 blk/CU
  float* As  = smem;                          // [128][68] k-major: As[k][row]
  float* Es  = smem + DDIM * AS_STRIDE;       // [16][260] k-major: Es[k][code]
  float* Ens = Es + KC * ES_STRIDE;           // [256] e-norms of current chunk
  // Reduction overlay (reuses Es/Ens region after the main loop):
  float* red_v = Es;                          // [64][33]
  int*   red_i = (int*)(Es + 64 * 33);        // [64][33]
  int*   bcode = (int*)(Es + 2 * 64 * 33);    // [64]

  const int tid = threadIdx.x;
  const int tx = tid & 31;   // code group (32)
  const int ty = tid >> 5;   // row group (8)
  const int row_base = blockIdx.x * MROWS;

  // Stage A tile transposed to k-major, once. (One-time 8-way store conflicts: negligible.)
  #pragma unroll
  for (int it = 0; it < 8; ++it) {
    int idx = it * 256 + tid;
    int r = idx >> 5;          // 0..63
    int f4 = idx & 31;         // 0..31 float4 along k
    float4 v = *(const float4*)(rin + (size_t)(row_base + r) * DDIM + f4 * 4);
    As[(4 * f4 + 0) * AS_STRIDE + r] = v.x;
    As[(4 * f4 + 1) * AS_STRIDE + r] = v.y;
    As[(4 * f4 + 2) * AS_STRIDE + r] = v.z;
    As[(4 * f4 + 3) * AS_STRIDE + r] = v.w;
  }

  float best[8];
  int bidx[8];
  #pragma unroll
  for (int i = 0; i < 8; ++i) { best[i] = -3.0e38f; bidx[i] = 0x7fffffff; }

  for (int nc = 0; nc < KCODES / NCHUNK; ++nc) {   // 4 chunks of 256 codes
    float acc[8][8];
    #pragma unroll
    for (int i = 0; i < 8; ++i)
      #pragma unroll
      for (int j = 0; j < 8; ++j) acc[i][j] = 0.0f;

    for (int kc = 0; kc < DDIM / KC; ++kc) {       // 8 chunks of 16 k-dims
      __syncthreads();
      // Stage E chunk transposed to k-major. Store banks: (16*f4 + 4j + c)%32 with
      // f4 aliasing only 2-way -> conflict-free.
      #pragma unroll
      for (int it = 0; it < 4; ++it) {
        int idx = it * 256 + tid;
        int c = idx >> 2;      // 0..255
        int f4 = idx & 3;      // 0..3 float4 along this k-slice
        float4 v = *(const float4*)(embed + (size_t)(nc * NCHUNK + c) * DDIM + kc * KC + f4 * 4);
        Es[(4 * f4 + 0) * ES_STRIDE + c] = v.x;
        Es[(4 * f4 + 1) * ES_STRIDE + c] = v.y;
        Es[(4 * f4 + 2) * ES_STRIDE + c] = v.z;
        Es[(4 * f4 + 3) * ES_STRIDE + c] = v.w;
      }
      if (kc == 0) Ens[tid] = enorm[nc * NCHUNK + tid];
      __syncthreads();

      const float* pa = As + kc * KC * AS_STRIDE + ty * 8;
      const float* pe = Es + 4 * tx;
      #pragma unroll 4
      for (int k = 0; k < KC; ++k) {
        float4 a0 = *(const float4*)(pa + k * AS_STRIDE);
        float4 a1 = *(const float4*)(pa + k * AS_STRIDE + 4);
        float4 e0 = *(const float4*)(pe + k * ES_STRIDE);
        float4 e1 = *(const float4*)(pe + k * ES_STRIDE + 128);
        float aa[8] = {a0.x, a0.y, a0.z, a0.w, a1.x, a1.y, a1.z, a1.w};
        float ee[8] = {e0.x, e0.y, e0.z, e0.w, e1.x, e1.y, e1.z, e1.w};
        #pragma unroll
        for (int i = 0; i < 8; ++i)
          #pragma unroll
          for (int j = 0; j < 8; ++j)
            acc[i][j] = fmaf(aa[i], ee[j], acc[i][j]);
      }
    }

    // Epilogue for this code chunk: dist = 2*dot - ||e||^2, running argmax
    // (strict >, ties -> lowest global index, matching jnp.argmax first-occurrence).
    #pragma unroll
    for (int j = 0; j < 8; ++j) {
      int c_local = (j < 4) ? (4 * tx + j) : (128 + 4 * tx + (j - 4));
      float en = Ens[c_local];
      int cg = nc * NCHUNK + c_local;
      #pragma unroll
      for (int i = 0; i < 8; ++i) {
        float dist = 2.0f * acc[i][j] - en;
        if (dist > best[i] || (dist == best[i] && cg < bidx[i])) {
          best[i] = dist; bidx[i] = cg;
        }
      }
    }
  }

  __syncthreads();   // done with Es/Ens; overlay reduction arrays
  #pragma unroll
  for (int i = 0; i < 8; ++i) {
    red_v[(ty * 8 + i) * 33 + tx] = best[i];
    red_i[(ty * 8 + i) * 33 + tx] = bidx[i];
  }
  __syncthreads();
  if (tid < MROWS) {
    float bv = red_v[tid * 33];
    int bi = red_i[tid * 33];
    #pragma unroll
    for (int t = 1; t < 32; ++t) {
      float v = red_v[tid * 33 + t];
      int ix = red_i[tid * 33 + t];
      if (v > bv || (v == bv && ix < bi)) { bv = v; bi = ix; }
    }
    codes[row_base + tid] = bi;
    bcode[tid] = bi;
  }
  __syncthreads();

  // Residual update: rout[r][d] = As[d][r] - embed[code[r]][d], coalesced global access.
  #pragma unroll
  for (int it = 0; it < 32; ++it) {
    int idx = it * 256 + tid;
    int r = idx >> 7;
    int d = idx & 127;
    float e = embed[(size_t)bcode[r] * DDIM + d];
    rout[(size_t)(row_base + r) * DDIM + d] = As[d * AS_STRIDE + r] - e;
  }
}

extern "C" void kernel_launch(void* const* d_in, const int* in_sizes, int n_in,
                              void* d_out, int out_size, void* d_ws, size_t ws_size,
                              hipStream_t stream) {
  (void)in_sizes; (void)n_in; (void)out_size;
  const float* x = (const float*)d_in[0];
  const float* embed = (const float*)d_in[1];
  int* codes = (int*)d_out;

  const size_t resid_elems = (size_t)M_TOTAL * DDIM;
  const bool ws_ok = ws_size >= (resid_elems + (size_t)NQ * KCODES) * sizeof(float);
  float* resid = ws_ok ? (float*)d_ws : (float*)d_in[0];
  float* enorm = ws_ok ? ((float*)d_ws + resid_elems) : (float*)d_ws;

  enorm_kernel<<<dim3(NQ * KCODES / 4), dim3(256), 0, stream>>>(embed, enorm);

  for (int q = 0; q < NQ; ++q) {
    const float* rin = (q == 0) ? x : resid;
    rvq_stage_kernel<<<dim3(M_TOTAL / MROWS), dim3(256), 0, stream>>>(
        rin, resid,
        embed + (size_t)q * KCODES * DDIM,
        enorm + (size_t)q * KCODES,
        codes + (size_t)q * M_TOTAL);
  }
}